// Round 10
// baseline (142.866 us; speedup 1.0000x reference)
//
#include <hip/hip_runtime.h>
#include <math.h>

// Problem constants (ProbAttention: B=4, H=8, L=2048, D=64, factor=5)
#define B_ 4
#define H_ 8
#define L_ 2048
#define D_ 64
#define SK_ 40      // sample_k = 5*ceil(ln(2048)) = 40
#define U_ 40       // u = min(5*ceil(ln(2048)), 2048) = 40
#define NSEG 32
#define SEGLEN 64   // NSEG*SEGLEN = L_
#define CK 256      // keys per chunk in batched attention
#define NCHUNK (L_ / CK)   // 8
#define QG 8        // queries per attention block
#define NQG (U_ / QG)      // 5

// ---------------------------------------------------------------------------
// Kernel 1 (v6): M scores. One WAVE per query, 8 lanes per sample.
// At the measured random-gather floor (~17 TB/s effective L2 gather; 5
// structural variants all land 40-47 us). Do not touch.
// ---------------------------------------------------------------------------
__global__ __launch_bounds__(1024) void k_compute_M(
    const float* __restrict__ Q, const float* __restrict__ K,
    const int* __restrict__ idxs, float* __restrict__ M) {
  int blk = blockIdx.x;            // 0..4095
  int x = blk & 7;                 // intended XCD (dispatch round-robins %8)
  int j = blk >> 3;                // 0..511
  int bh = ((j >> 7) << 3) | x;    // 4 heads per XCD-group; K stays in L2
  int qc = j & 127;                // query-chunk within head
  int wave = threadIdx.x >> 6;     // 0..15
  int lane = threadIdx.x & 63;
  int q = qc * 16 + wave;

  int g  = lane >> 3;              // sample group 0..7
  int li = lane & 7;               // lane within group

  const float4* qrow = (const float4*)(Q + ((size_t)bh * L_ + q) * D_);
  float4 qa = qrow[li], qb = qrow[li + 8];
  int myidx = (lane < SK_) ? idxs[q * SK_ + lane] : 0;
  const float* Kb = K + (size_t)bh * L_ * D_;

  int kis[5];
#pragma unroll
  for (int t = 0; t < 5; ++t) kis[t] = __shfl(myidx, t * 8 + g, 64);

  float4 ka[5], kb[5];
#pragma unroll
  for (int t = 0; t < 5; ++t) {
    const float4* kr = (const float4*)(Kb + (size_t)kis[t] * D_);
    ka[t] = kr[li];
    kb[t] = kr[li + 8];
  }

  float d[5];
#pragma unroll
  for (int t = 0; t < 5; ++t) {
    d[t] = qa.x * ka[t].x + qa.y * ka[t].y + qa.z * ka[t].z + qa.w * ka[t].w
         + qb.x * kb[t].x + qb.y * kb[t].y + qb.z * kb[t].z + qb.w * kb[t].w;
  }
  float mx = -INFINITY, sm = 0.f;
#pragma unroll
  for (int t = 0; t < 5; ++t) {
    float v = d[t];
    v += __shfl_xor(v, 1, 64);
    v += __shfl_xor(v, 2, 64);
    v += __shfl_xor(v, 4, 64);     // all 8 lanes of group hold full dot
    mx = fmaxf(mx, v);
    sm += v;
  }
  mx = fmaxf(mx, __shfl_xor(mx, 8, 64));
  mx = fmaxf(mx, __shfl_xor(mx, 16, 64));
  mx = fmaxf(mx, __shfl_xor(mx, 32, 64));
  sm += __shfl_xor(sm, 8, 64);
  sm += __shfl_xor(sm, 16, 64);
  sm += __shfl_xor(sm, 32, 64);
  if (lane == 0) M[bh * L_ + q] = mx - sm * (1.0f / (float)L_);
}

// ---------------------------------------------------------------------------
// Kernel 2 (v2): top-U_ per head via 4-pass MSD radix select.
// ---------------------------------------------------------------------------
__global__ __launch_bounds__(1024) void k_topk(
    const float* __restrict__ M, int* __restrict__ Mtop) {
  __shared__ unsigned keys[L_];    // 8 KB
  __shared__ int hist[256];
  __shared__ int Gs[256];
  __shared__ unsigned ctl_prefix;
  __shared__ int ctl_need, ctl_cnt, ctl_min;
  __shared__ int wmin[16];
  int bh = blockIdx.x;
  int tid = threadIdx.x;

  for (int i = tid; i < L_; i += 1024) {
    unsigned u = __float_as_uint(M[bh * L_ + i]);
    keys[i] = (u & 0x80000000u) ? ~u : (u | 0x80000000u);
  }
  if (tid == 0) { ctl_prefix = 0u; ctl_need = U_; ctl_cnt = 0; }
  __syncthreads();

  unsigned prefix = 0u, pmask = 0u;
#pragma unroll
  for (int pass = 0; pass < 4; ++pass) {
    int shift = 24 - 8 * pass;
    if (tid < 256) hist[tid] = 0;
    __syncthreads();
    for (int i = tid; i < L_; i += 1024) {
      unsigned k = keys[i];
      if ((k & pmask) == prefix) atomicAdd(&hist[(k >> shift) & 0xffu], 1);
    }
    __syncthreads();
    if (tid < 64) {
      int b0 = tid * 4;
      int h0 = hist[b0], h1 = hist[b0 + 1], h2 = hist[b0 + 2], h3 = hist[b0 + 3];
      int gs = h0 + h1 + h2 + h3;
      int S = gs;
#pragma unroll
      for (int d = 1; d < 64; d <<= 1) {
        int v = __shfl_down(S, d, 64);
        if (tid + d < 64) S += v;
      }
      int E = S - gs;              // keys in groups strictly after this group
      Gs[b0 + 3] = E;
      Gs[b0 + 2] = E + h3;
      Gs[b0 + 1] = E + h3 + h2;
      Gs[b0 + 0] = E + h3 + h2 + h1;
    }
    __syncthreads();
    int need = ctl_need;
    if (tid < 256) {
      int G = Gs[tid], h = hist[tid];
      if (G < need && need <= G + h) {   // unique bin
        ctl_prefix = prefix | ((unsigned)tid << shift);
        ctl_need = need - G;
      }
    }
    __syncthreads();
    prefix = ctl_prefix;
    pmask |= (0xffu << shift);
  }

  unsigned v40 = prefix;           // exact 40th-largest key
  int tiesNeeded = ctl_need;
  __syncthreads();

  for (int i = tid; i < L_; i += 1024) {
    if (keys[i] > v40) {
      int slot = atomicAdd(&ctl_cnt, 1);
      Mtop[bh * U_ + slot] = i;
    }
  }
  __syncthreads();
  int base = ctl_cnt;
  int last = -1;
  for (int t = 0; t < tiesNeeded; ++t) {
    int lmin = 0x7fffffff;
    for (int i = tid; i < L_; i += 1024)
      if (keys[i] == v40 && i > last) lmin = min(lmin, i);
#pragma unroll
    for (int d = 32; d > 0; d >>= 1) lmin = min(lmin, __shfl_xor(lmin, d, 64));
    if ((tid & 63) == 0) wmin[tid >> 6] = lmin;
    __syncthreads();
    if (tid == 0) {
      int m = wmin[0];
      for (int w = 1; w < 16; ++w) m = min(m, wmin[w]);
      Mtop[bh * U_ + base + t] = m;
      ctl_min = m;
    }
    __syncthreads();
    last = ctl_min;
  }
}

// ---------------------------------------------------------------------------
// Kernel 3a: per-segment sums of V along L. One wave per (bh, seg), lane = d.
// ---------------------------------------------------------------------------
__global__ __launch_bounds__(256) void k_segsum(
    const float* __restrict__ V, float* __restrict__ segsum) {
  int gw = (blockIdx.x * blockDim.x + threadIdx.x) >> 6;  // global wave id
  int lane = threadIdx.x & 63;
  int seg = gw & (NSEG - 1);
  int bh  = gw >> 5;
  const float* Vb = V + ((size_t)bh * L_ + seg * SEGLEN) * D_;
  float s = 0.f;
#pragma unroll 8
  for (int l = 0; l < SEGLEN; ++l) s += Vb[(size_t)l * D_ + lane];
  segsum[((size_t)bh * NSEG + seg) * D_ + lane] = s;
}

// ---------------------------------------------------------------------------
// Kernel 3b: cumsum within segment + prefix offset; write to out (B,L,H,D).
// ---------------------------------------------------------------------------
__global__ __launch_bounds__(256) void k_cumsum(
    const float* __restrict__ V, const float* __restrict__ segsum,
    float* __restrict__ out) {
  int gw = (blockIdx.x * blockDim.x + threadIdx.x) >> 6;
  int lane = threadIdx.x & 63;
  int seg = gw & (NSEG - 1);
  int bh  = gw >> 5;
  int b = bh >> 3, h = bh & 7;
  float off = 0.f;
  for (int s = 0; s < seg; ++s)
    off += segsum[((size_t)bh * NSEG + s) * D_ + lane];
  const float* Vb = V + ((size_t)bh * L_ + seg * SEGLEN) * D_;
  float run = off;
  for (int l = 0; l < SEGLEN; ++l) {
    run += Vb[(size_t)l * D_ + lane];
    int gl = seg * SEGLEN + l;
    out[(((size_t)b * L_ + gl) * H_ + h) * D_ + lane] = run;
  }
}

// ---------------------------------------------------------------------------
// Kernel 4 (v3): FUSED online-softmax causal attention for the selected rows.
// One block per (bh, query-group of 8) = 160 blocks, 256 threads.
// Iterates the 8 K-chunks with flash-style running (m, s) per query and
// per-wave register PV accumulators -> no global partials, no reduce kernel.
// Per chunk: phase1 thread-per-key scores (K row in VGPRs, Q broadcast from
// LDS); phase2 owner-wave computes chunk max/sum + online merge factors;
// phase3 wave w covers keys [w*64,+64) for all 8 queries, rescale+accumulate.
// ---------------------------------------------------------------------------
__global__ __launch_bounds__(256) void k_attn(
    const float* __restrict__ Q, const float* __restrict__ K,
    const float* __restrict__ V, const int* __restrict__ Mtop,
    float* __restrict__ out) {
  // XCD-chunked mapping: all 5 blocks of a head on one XCD (4 heads/XCD)
  int blk = blockIdx.x;            // 0..159
  int x = blk & 7;
  int j = blk >> 3;                // 0..19
  int bh = (j / NQG) * 8 + x;
  int qg = j % NQG;                // query group 0..4
  int b = bh >> 3, h = bh & 7;

  int tid = threadIdx.x;
  int w = tid >> 6, lane = tid & 63;
  __shared__ float Qs[QG][D_];         // 2 KB
  __shared__ float P[QG][CK];          // 8 KB
  __shared__ float pvred[4][QG][D_];   // 8 KB
  __shared__ float scaleO[QG];         // old-acc rescale per chunk
  __shared__ float pfac[QG];           // chunk-partial factor exp(m_c - m_new)
  __shared__ float sfin[QG];           // final denominators
  __shared__ int q0s[QG];
  if (tid < QG) q0s[tid] = Mtop[bh * U_ + qg * QG + tid];
  __syncthreads();
  for (int i = tid; i < QG * D_; i += 256) {
    int u = i >> 6, d = i & 63;
    Qs[u][d] = Q[((size_t)bh * L_ + q0s[u]) * D_ + d];
  }

  // online state: wave w owns queries 2w, 2w+1 (m_run, s_run in registers)
  float m_run[2] = {-INFINITY, -INFINITY};
  float s_run[2] = {0.f, 0.f};
  // per-wave PV partial accumulators (keys [w*64,+64) of each chunk), lane=d
  float acc[QG];
#pragma unroll
  for (int u = 0; u < QG; ++u) acc[u] = 0.f;
  __syncthreads();

  for (int c = 0; c < NCHUNK; ++c) {
    // ---- phase 1: scores, thread-per-key
    int kg = c * CK + tid;
    const float4* kr = (const float4*)(K + ((size_t)bh * L_ + kg) * D_);
    float4 kv[16];
#pragma unroll
    for (int j4 = 0; j4 < 16; ++j4) kv[j4] = kr[j4];
#pragma unroll
    for (int u = 0; u < QG; ++u) {
      float a = 0.f;
#pragma unroll
      for (int j4 = 0; j4 < 16; ++j4) {
        float4 qv = *(const float4*)&Qs[u][j4 * 4];
        a += qv.x * kv[j4].x + qv.y * kv[j4].y + qv.z * kv[j4].z + qv.w * kv[j4].w;
      }
      P[u][tid] = (kg <= q0s[u]) ? a : -INFINITY;
    }
    __syncthreads();

    // ---- phase 2: owner wave computes chunk max/sum + online merge factors
#pragma unroll
    for (int uu = 0; uu < 2; ++uu) {
      int u = w * 2 + uu;
      float v0 = P[u][lane], v1 = P[u][lane + 64];
      float v2 = P[u][lane + 128], v3 = P[u][lane + 192];
      float m = fmaxf(fmaxf(v0, v1), fmaxf(v2, v3));
      for (int o = 32; o > 0; o >>= 1) m = fmaxf(m, __shfl_xor(m, o, 64));
      float e0 = (v0 == -INFINITY) ? 0.f : expf(v0 - m);
      float e1 = (v1 == -INFINITY) ? 0.f : expf(v1 - m);
      float e2 = (v2 == -INFINITY) ? 0.f : expf(v2 - m);
      float e3 = (v3 == -INFINITY) ? 0.f : expf(v3 - m);
      float s = e0 + e1 + e2 + e3;
      for (int o = 32; o > 0; o >>= 1) s += __shfl_xor(s, o, 64);
      P[u][lane] = e0; P[u][lane + 64] = e1;
      P[u][lane + 128] = e2; P[u][lane + 192] = e3;
      // online merge (guard: fully-masked chunk -> m == -inf)
      float so, pf;
      if (m == -INFINITY) {
        so = 1.f; pf = 0.f;                    // nothing to add
      } else {
        float mnew = fmaxf(m_run[uu], m);
        so = (m_run[uu] == -INFINITY) ? 0.f : expf(m_run[uu] - mnew);
        pf = expf(m - mnew);
        m_run[uu] = mnew;
      }
      s_run[uu] = s_run[uu] * so + s * pf;
      if (lane == 0) { scaleO[u] = so; pfac[u] = pf; }
    }
    __syncthreads();

    // ---- phase 3: wave w covers keys [c*CK + w*64, +64) for all 8 queries
    const float* Vb = V + ((size_t)bh * L_ + c * CK + w * 64) * D_;
    float pv[QG];
#pragma unroll
    for (int u = 0; u < QG; ++u) pv[u] = 0.f;
    for (int k4 = 0; k4 < 16; ++k4) {
      float4 pw[QG];
#pragma unroll
      for (int u = 0; u < QG; ++u) pw[u] = *(const float4*)&P[u][w * 64 + k4 * 4];
      float va = Vb[(size_t)(k4 * 4 + 0) * D_ + lane];
      float vb = Vb[(size_t)(k4 * 4 + 1) * D_ + lane];
      float vc = Vb[(size_t)(k4 * 4 + 2) * D_ + lane];
      float vd = Vb[(size_t)(k4 * 4 + 3) * D_ + lane];
#pragma unroll
      for (int u = 0; u < QG; ++u)
        pv[u] += pw[u].x * va + pw[u].y * vb + pw[u].z * vc + pw[u].w * vd;
    }
#pragma unroll
    for (int u = 0; u < QG; ++u)
      acc[u] = acc[u] * scaleO[u] + pv[u] * pfac[u];
    __syncthreads();   // P/scaleO/pfac free for next chunk
  }

  // ---- final: cross-wave reduce, normalize, scatter
#pragma unroll
  for (int u = 0; u < QG; ++u) pvred[w][u][lane] = acc[u];
  if (lane == 0) { sfin[w * 2] = s_run[0]; sfin[w * 2 + 1] = s_run[1]; }
  __syncthreads();
#pragma unroll
  for (int uu = 0; uu < 2; ++uu) {
    int u = w * 2 + uu;
    float tot = pvred[0][u][lane] + pvred[1][u][lane] +
                pvred[2][u][lane] + pvred[3][u][lane];
    out[(((size_t)b * L_ + q0s[u]) * H_ + h) * D_ + lane] = tot / sfin[u];
  }
}

extern "C" void kernel_launch(void* const* d_in, const int* in_sizes, int n_in,
                              void* d_out, int out_size, void* d_ws, size_t ws_size,
                              hipStream_t stream) {
  const float* Q = (const float*)d_in[0];
  const float* K = (const float*)d_in[1];
  const float* V = (const float*)d_in[2];
  const int* idxs = (const int*)d_in[3];
  float* out = (float*)d_out;

  char* ws = (char*)d_ws;
  float* M      = (float*)(ws + 0);              // 256 KB
  float* segsum = (float*)(ws + 262144);         // 256 KB
  int*   Mtop   = (int*)(ws + 524288);           // 5 KB

  // 1) M scores: one wave per (bh,q), 16 queries per 1024-thread block
  k_compute_M<<<(B_ * H_ * L_) / 16, 1024, 0, stream>>>(Q, K, idxs, M);
  // 2) top-k per head (radix select)
  k_topk<<<B_ * H_, 1024, 0, stream>>>(M, Mtop);
  // 3) cumsum of V -> out (transposed)
  k_segsum<<<(B_ * H_ * NSEG) / 4, 256, 0, stream>>>(V, segsum);
  k_cumsum<<<(B_ * H_ * NSEG) / 4, 256, 0, stream>>>(V, segsum, out);
  // 4) fused online-softmax attention on selected rows, overwrite out rows
  k_attn<<<B_ * H_ * NQG, 256, 0, stream>>>(Q, K, V, Mtop, out);
}

// Round 11
// 69.178 us; speedup vs baseline: 2.0652x; 2.0652x over previous
//
#include <hip/hip_runtime.h>
#include <math.h>

// Problem constants (ProbAttention: B=4, H=8, L=2048, D=64, factor=5)
#define B_ 4
#define H_ 8
#define L_ 2048
#define D_ 64
#define SK_ 40      // sample_k = 5*ceil(ln(2048)) = 40
#define U_ 40       // u = min(5*ceil(ln(2048)), 2048) = 40
#define CK 256      // keys per chunk in batched attention
#define NCHUNK (L_ / CK)   // 8
#define QG 8        // queries per attention block
#define NQG (U_ / QG)      // 5
#define CSB 32      // cumsum blocks (one per bh), dispatched FIRST

// ---------------------------------------------------------------------------
// Kernel 1 (v7): heterogeneous fused launch.
//  blocks 0..31   : full V-cumsum for head bh=blockIdx (independent of M work;
//                   runs concurrently, hidden under the gather-bound M blocks)
//  blocks 32..4127: M-score blocks (identical to v6, blk = blockIdx-32; the
//                   -32 shift preserves blk&7 XCD mapping since 32%8==0)
// ---------------------------------------------------------------------------
__global__ __launch_bounds__(1024) void k_mcs(
    const float* __restrict__ Q, const float* __restrict__ K,
    const int* __restrict__ idxs, const float* __restrict__ V,
    float* __restrict__ M, float* __restrict__ out) {
  if (blockIdx.x < CSB) {
    // ---- cumsum path: one block per bh, 16 segments x 64 dims
    __shared__ float segtot[16][64];
    int bh = blockIdx.x;
    int b = bh >> 3, h = bh & 7;
    int t = threadIdx.x;
    int seg = t >> 6, d = t & 63;      // wave = one segment, lane = dim
    const float* Vb = V + (size_t)bh * L_ * D_;
    int base = seg * 128;
    float s = 0.f;
    for (int l = 0; l < 128; ++l) s += Vb[(size_t)(base + l) * D_ + d];
    segtot[seg][d] = s;
    __syncthreads();
    float run = 0.f;
    for (int ss = 0; ss < seg; ++ss) run += segtot[ss][d];
    for (int l = 0; l < 128; ++l) {
      int gl = base + l;
      run += Vb[(size_t)gl * D_ + d];
      out[(((size_t)b * L_ + gl) * H_ + h) * D_ + d] = run;
    }
    return;
  }

  // ---- M-score path (v6 structure, at the measured random-gather floor)
  int blk = blockIdx.x - CSB;      // 0..4095
  int x = blk & 7;                 // intended XCD (dispatch round-robins %8)
  int j = blk >> 3;                // 0..511
  int bh = ((j >> 7) << 3) | x;    // 4 heads per XCD-group; K stays in L2
  int qc = j & 127;                // query-chunk within head
  int wave = threadIdx.x >> 6;     // 0..15
  int lane = threadIdx.x & 63;
  int q = qc * 16 + wave;

  int g  = lane >> 3;              // sample group 0..7
  int li = lane & 7;               // lane within group

  const float4* qrow = (const float4*)(Q + ((size_t)bh * L_ + q) * D_);
  float4 qa = qrow[li], qb = qrow[li + 8];
  int myidx = (lane < SK_) ? idxs[q * SK_ + lane] : 0;
  const float* Kb = K + (size_t)bh * L_ * D_;

  int kis[5];
#pragma unroll
  for (int t = 0; t < 5; ++t) kis[t] = __shfl(myidx, t * 8 + g, 64);

  float4 ka[5], kb[5];
#pragma unroll
  for (int t = 0; t < 5; ++t) {
    const float4* kr = (const float4*)(Kb + (size_t)kis[t] * D_);
    ka[t] = kr[li];
    kb[t] = kr[li + 8];
  }

  float d[5];
#pragma unroll
  for (int t = 0; t < 5; ++t) {
    d[t] = qa.x * ka[t].x + qa.y * ka[t].y + qa.z * ka[t].z + qa.w * ka[t].w
         + qb.x * kb[t].x + qb.y * kb[t].y + qb.z * kb[t].z + qb.w * kb[t].w;
  }
  float mx = -INFINITY, sm = 0.f;
#pragma unroll
  for (int t = 0; t < 5; ++t) {
    float v = d[t];
    v += __shfl_xor(v, 1, 64);
    v += __shfl_xor(v, 2, 64);
    v += __shfl_xor(v, 4, 64);     // all 8 lanes of group hold full dot
    mx = fmaxf(mx, v);
    sm += v;
  }
  mx = fmaxf(mx, __shfl_xor(mx, 8, 64));
  mx = fmaxf(mx, __shfl_xor(mx, 16, 64));
  mx = fmaxf(mx, __shfl_xor(mx, 32, 64));
  sm += __shfl_xor(sm, 8, 64);
  sm += __shfl_xor(sm, 16, 64);
  sm += __shfl_xor(sm, 32, 64);
  if (lane == 0) M[bh * L_ + q] = mx - sm * (1.0f / (float)L_);
}

// ---------------------------------------------------------------------------
// Kernel 2 (v2): top-U_ per head via 4-pass MSD radix select.
// ---------------------------------------------------------------------------
__global__ __launch_bounds__(1024) void k_topk(
    const float* __restrict__ M, int* __restrict__ Mtop) {
  __shared__ unsigned keys[L_];    // 8 KB
  __shared__ int hist[256];
  __shared__ int Gs[256];
  __shared__ unsigned ctl_prefix;
  __shared__ int ctl_need, ctl_cnt, ctl_min;
  __shared__ int wmin[16];
  int bh = blockIdx.x;
  int tid = threadIdx.x;

  for (int i = tid; i < L_; i += 1024) {
    unsigned u = __float_as_uint(M[bh * L_ + i]);
    keys[i] = (u & 0x80000000u) ? ~u : (u | 0x80000000u);
  }
  if (tid == 0) { ctl_prefix = 0u; ctl_need = U_; ctl_cnt = 0; }
  __syncthreads();

  unsigned prefix = 0u, pmask = 0u;
#pragma unroll
  for (int pass = 0; pass < 4; ++pass) {
    int shift = 24 - 8 * pass;
    if (tid < 256) hist[tid] = 0;
    __syncthreads();
    for (int i = tid; i < L_; i += 1024) {
      unsigned k = keys[i];
      if ((k & pmask) == prefix) atomicAdd(&hist[(k >> shift) & 0xffu], 1);
    }
    __syncthreads();
    if (tid < 64) {
      int b0 = tid * 4;
      int h0 = hist[b0], h1 = hist[b0 + 1], h2 = hist[b0 + 2], h3 = hist[b0 + 3];
      int gs = h0 + h1 + h2 + h3;
      int S = gs;
#pragma unroll
      for (int d = 1; d < 64; d <<= 1) {
        int v = __shfl_down(S, d, 64);
        if (tid + d < 64) S += v;
      }
      int E = S - gs;              // keys in groups strictly after this group
      Gs[b0 + 3] = E;
      Gs[b0 + 2] = E + h3;
      Gs[b0 + 1] = E + h3 + h2;
      Gs[b0 + 0] = E + h3 + h2 + h1;
    }
    __syncthreads();
    int need = ctl_need;
    if (tid < 256) {
      int G = Gs[tid], h = hist[tid];
      if (G < need && need <= G + h) {   // unique bin
        ctl_prefix = prefix | ((unsigned)tid << shift);
        ctl_need = need - G;
      }
    }
    __syncthreads();
    prefix = ctl_prefix;
    pmask |= (0xffu << shift);
  }

  unsigned v40 = prefix;           // exact 40th-largest key
  int tiesNeeded = ctl_need;
  __syncthreads();

  for (int i = tid; i < L_; i += 1024) {
    if (keys[i] > v40) {
      int slot = atomicAdd(&ctl_cnt, 1);
      Mtop[bh * U_ + slot] = i;
    }
  }
  __syncthreads();
  int base = ctl_cnt;
  int last = -1;
  for (int t = 0; t < tiesNeeded; ++t) {
    int lmin = 0x7fffffff;
    for (int i = tid; i < L_; i += 1024)
      if (keys[i] == v40 && i > last) lmin = min(lmin, i);
#pragma unroll
    for (int d = 32; d > 0; d >>= 1) lmin = min(lmin, __shfl_xor(lmin, d, 64));
    if ((tid & 63) == 0) wmin[tid >> 6] = lmin;
    __syncthreads();
    if (tid == 0) {
      int m = wmin[0];
      for (int w = 1; w < 16; ++w) m = min(m, wmin[w]);
      Mtop[bh * U_ + base + t] = m;
      ctl_min = m;
    }
    __syncthreads();
    last = ctl_min;
  }
}

// ---------------------------------------------------------------------------
// Kernel 4a (v2): batched causal attention partials.
// One block per (bh, K-chunk, query-group of 8). 1280 blocks.
// ---------------------------------------------------------------------------
__global__ __launch_bounds__(256) void k_attn_part(
    const float* __restrict__ Q, const float* __restrict__ K,
    const float* __restrict__ V, const int* __restrict__ Mtop,
    float* __restrict__ pm, float* __restrict__ ps, float* __restrict__ pacc) {
  // XCD-chunked mapping: all 40 blocks of a head on one XCD (4 heads/XCD)
  int blk = blockIdx.x;            // 0..1279
  int x = blk & 7;
  int j = blk >> 3;                // 0..159
  int bh = (j / 40) * 8 + x;
  int rem = j % 40;
  int c  = rem / NQG;              // K-chunk 0..7
  int qg = rem % NQG;              // query group 0..4

  int tid = threadIdx.x;
  int w = tid >> 6, lane = tid & 63;
  __shared__ float Qs[QG][D_];         // 2 KB
  __shared__ float P[QG][CK];          // 8 KB
  __shared__ float pvred[4][QG][D_];   // 8 KB
  __shared__ int q0s[QG];
  if (tid < QG) q0s[tid] = Mtop[bh * U_ + qg * QG + tid];
  __syncthreads();
  for (int i = tid; i < QG * D_; i += 256) {
    int u = i >> 6, d = i & 63;
    Qs[u][d] = Q[((size_t)bh * L_ + q0s[u]) * D_ + d];
  }
  __syncthreads();

  // phase 1: scores. thread owns key kg = c*CK + tid.
  int kg = c * CK + tid;
  const float4* kr = (const float4*)(K + ((size_t)bh * L_ + kg) * D_);
  float4 kv[16];
#pragma unroll
  for (int j4 = 0; j4 < 16; ++j4) kv[j4] = kr[j4];
#pragma unroll
  for (int u = 0; u < QG; ++u) {
    float acc = 0.f;
#pragma unroll
    for (int j4 = 0; j4 < 16; ++j4) {
      float4 qv = *(const float4*)&Qs[u][j4 * 4];
      acc += qv.x * kv[j4].x + qv.y * kv[j4].y + qv.z * kv[j4].z + qv.w * kv[j4].w;
    }
    P[u][tid] = (kg <= q0s[u]) ? acc : -INFINITY;
  }
  __syncthreads();

  // phase 2: wave w softmaxes queries 2w, 2w+1 (chunk-local m, s)
#pragma unroll
  for (int uu = 0; uu < 2; ++uu) {
    int u = w * 2 + uu;
    float v0 = P[u][lane], v1 = P[u][lane + 64];
    float v2 = P[u][lane + 128], v3 = P[u][lane + 192];
    float m = fmaxf(fmaxf(v0, v1), fmaxf(v2, v3));
    for (int o = 32; o > 0; o >>= 1) m = fmaxf(m, __shfl_xor(m, o, 64));
    float e0 = (v0 == -INFINITY) ? 0.f : expf(v0 - m);
    float e1 = (v1 == -INFINITY) ? 0.f : expf(v1 - m);
    float e2 = (v2 == -INFINITY) ? 0.f : expf(v2 - m);
    float e3 = (v3 == -INFINITY) ? 0.f : expf(v3 - m);
    float s = e0 + e1 + e2 + e3;
    for (int o = 32; o > 0; o >>= 1) s += __shfl_xor(s, o, 64);
    P[u][lane] = e0; P[u][lane + 64] = e1;
    P[u][lane + 128] = e2; P[u][lane + 192] = e3;
    if (lane == 0) {
      int p = (bh * NCHUNK + c) * U_ + qg * QG + u;
      pm[p] = m; ps[p] = s;
    }
  }
  __syncthreads();

  // phase 3: wave w covers keys [c*CK + w*64, +64) for all 8 queries, lane=d
  const float* Vb = V + ((size_t)bh * L_ + c * CK + w * 64) * D_;
  float acc[QG];
#pragma unroll
  for (int u = 0; u < QG; ++u) acc[u] = 0.f;
  for (int k4 = 0; k4 < 16; ++k4) {
    float4 pv[QG];
#pragma unroll
    for (int u = 0; u < QG; ++u) pv[u] = *(const float4*)&P[u][w * 64 + k4 * 4];
    float va = Vb[(size_t)(k4 * 4 + 0) * D_ + lane];
    float vb = Vb[(size_t)(k4 * 4 + 1) * D_ + lane];
    float vc = Vb[(size_t)(k4 * 4 + 2) * D_ + lane];
    float vd = Vb[(size_t)(k4 * 4 + 3) * D_ + lane];
#pragma unroll
    for (int u = 0; u < QG; ++u)
      acc[u] += pv[u].x * va + pv[u].y * vb + pv[u].z * vc + pv[u].w * vd;
  }
#pragma unroll
  for (int u = 0; u < QG; ++u) pvred[w][u][lane] = acc[u];
  __syncthreads();
  // final: wave w writes queries 2w, 2w+1
#pragma unroll
  for (int uu = 0; uu < 2; ++uu) {
    int u = w * 2 + uu;
    float tot = pvred[0][u][lane] + pvred[1][u][lane] +
                pvred[2][u][lane] + pvred[3][u][lane];
    int p = (bh * NCHUNK + c) * U_ + qg * QG + u;
    pacc[(size_t)p * 64 + lane] = tot;
  }
}

// ---------------------------------------------------------------------------
// Kernel 4b: merge chunk partials, normalize, scatter into out.
// ---------------------------------------------------------------------------
__global__ __launch_bounds__(256) void k_attn_reduce(
    const float* __restrict__ pm, const float* __restrict__ ps,
    const float* __restrict__ pacc, const int* __restrict__ Mtop,
    float* __restrict__ out) {
  int g = blockIdx.x * 4 + (threadIdx.x >> 6);  // (bh, u) pair
  int lane = threadIdx.x & 63;
  int bh = g / U_, u = g % U_;
  int b = bh >> 3, h = bh & 7;
  int q0 = Mtop[bh * U_ + u];
  float pmv[NCHUNK];
  float M = -INFINITY;
#pragma unroll
  for (int c = 0; c < NCHUNK; ++c) {
    pmv[c] = pm[(bh * NCHUNK + c) * U_ + u];
    M = fmaxf(M, pmv[c]);
  }
  float T = 0.f, o = 0.f;
#pragma unroll
  for (int c = 0; c < NCHUNK; ++c) {
    float wgt = (pmv[c] == -INFINITY) ? 0.f : expf(pmv[c] - M);
    T += ps[(bh * NCHUNK + c) * U_ + u] * wgt;
    o += pacc[((size_t)(bh * NCHUNK + c) * U_ + u) * 64 + lane] * wgt;
  }
  out[(((size_t)b * L_ + q0) * H_ + h) * D_ + lane] = o / T;
}

extern "C" void kernel_launch(void* const* d_in, const int* in_sizes, int n_in,
                              void* d_out, int out_size, void* d_ws, size_t ws_size,
                              hipStream_t stream) {
  const float* Q = (const float*)d_in[0];
  const float* K = (const float*)d_in[1];
  const float* V = (const float*)d_in[2];
  const int* idxs = (const int*)d_in[3];
  float* out = (float*)d_out;

  char* ws = (char*)d_ws;
  float* M      = (float*)(ws + 0);              // 256 KB
  int*   Mtop   = (int*)(ws + 262144);           // 5 KB (pad to 8 KB)
  float* pm     = (float*)(ws + 270336);         // 40 KB
  float* ps     = (float*)(ws + 311296);         // 40 KB
  float* pacc   = (float*)(ws + 352256);         // 2.62 MB

  // 1) fused: V-cumsum (blocks 0..31, starts immediately) + M scores
  k_mcs<<<CSB + (B_ * H_ * L_) / 16, 1024, 0, stream>>>(Q, K, idxs, V, M, out);
  // 2) top-k per head (radix select)
  k_topk<<<B_ * H_, 1024, 0, stream>>>(M, Mtop);
  // 3) batched causal attention on selected rows (partials + reduce)
  k_attn_part<<<B_ * H_ * NCHUNK * NQG, 256, 0, stream>>>(Q, K, V, Mtop, pm, ps, pacc);
  k_attn_reduce<<<(B_ * H_ * U_) / 4, 256, 0, stream>>>(pm, ps, pacc, Mtop, out);
}